// Round 7
// baseline (121.704 us; speedup 1.0000x reference)
//
#include <hip/hip_runtime.h>
#include <hip/hip_bf16.h>
#include <stdint.h>

#define N_PTS   4096
#define M_CODES 4096
#define ZDIM    1024
#define BM 128
#define BN 128
#define BK 32    // per slice; 2 slices staged per barrier pair
#define GRID_GEMM ((N_PTS / BM) * (M_CODES / BN))   // 1024

typedef __attribute__((ext_vector_type(8))) short bf16x8;
typedef __attribute__((ext_vector_type(4))) float f32x4;

__device__ __forceinline__ unsigned short f2bf(float f) {
    __hip_bfloat16 h = __float2bfloat16(f);
    return *reinterpret_cast<unsigned short*>(&h);
}

// order-preserving float -> uint map (monotone): enables atomicMin on uint
__device__ __forceinline__ unsigned enc_f32(float f) {
    unsigned u = __float_as_uint(f);
    return (u & 0x80000000u) ? ~u : (u | 0x80000000u);
}
__device__ __forceinline__ float dec_f32(unsigned e) {
    unsigned u = (e & 0x80000000u) ? (e ^ 0x80000000u) : ~e;
    return __uint_as_float(u);
}

// ---------------------------------------------------------------------------
// prep: fp32 -> bf16 convert + row sum-of-squares (R5-proven, unchanged).
// 1024 blocks x 256 threads; 8 rows/block, no LDS/syncthreads/atomics/fences.
// Blocks 0..15 init min_enc; block 16 zeroes the done-counter (race-free:
// only the gemm kernel touches ctrl afterwards).
// ---------------------------------------------------------------------------
__global__ __launch_bounds__(256) void prep_kernel(
    const float* __restrict__ z, const float* __restrict__ e,
    unsigned short* __restrict__ zb, unsigned short* __restrict__ eb,
    float* __restrict__ zsq, float* __restrict__ esq,
    unsigned* __restrict__ min_enc, unsigned* __restrict__ ctrl) {
    const int t = threadIdx.x;
    const int b = blockIdx.x;
    if (b < 16) min_enc[b * 256 + t] = 0xFFFFFFFFu;  // encodes "+huge"
    if (b == 16 && t == 0) ctrl[0] = 0u;

    const int w = t >> 6, lane = t & 63;
    const bool is_z = b < 512;
    #pragma unroll
    for (int r2 = 0; r2 < 2; r2++) {
        const int rr = (b & 511) * 8 + w * 2 + r2;
        const float4* s4 =
            reinterpret_cast<const float4*>((is_z ? z : e) + (size_t)rr * ZDIM);
        ushort4* d4 =
            reinterpret_cast<ushort4*>((is_z ? zb : eb) + (size_t)rr * ZDIM);
        float4 v0 = s4[lane], v1 = s4[64 + lane], v2 = s4[128 + lane],
               v3 = s4[192 + lane];
        ushort4 o0, o1, o2, o3;
        o0.x = f2bf(v0.x); o0.y = f2bf(v0.y); o0.z = f2bf(v0.z); o0.w = f2bf(v0.w);
        o1.x = f2bf(v1.x); o1.y = f2bf(v1.y); o1.z = f2bf(v1.z); o1.w = f2bf(v1.w);
        o2.x = f2bf(v2.x); o2.y = f2bf(v2.y); o2.z = f2bf(v2.z); o2.w = f2bf(v2.w);
        o3.x = f2bf(v3.x); o3.y = f2bf(v3.y); o3.z = f2bf(v3.z); o3.w = f2bf(v3.w);
        d4[lane] = o0; d4[64 + lane] = o1; d4[128 + lane] = o2; d4[192 + lane] = o3;
        float s = v0.x * v0.x + v0.y * v0.y + v0.z * v0.z + v0.w * v0.w
                + v1.x * v1.x + v1.y * v1.y + v1.z * v1.z + v1.w * v1.w
                + v2.x * v2.x + v2.y * v2.y + v2.z * v2.z + v2.w * v2.w
                + v3.x * v3.x + v3.y * v3.y + v3.z * v3.z + v3.w * v3.w;
        #pragma unroll
        for (int off = 1; off < 64; off <<= 1) s += __shfl_xor(s, off, 64);
        if (lane == 0) {
            if (is_z) zsq[rr] = s; else esq[rr] = s;
        }
    }
}

// ---------------------------------------------------------------------------
// gemm_min: R6-proven inner loop (2x BK=32 slices per barrier pair, 32 MFMA
// per barrier, lane-contiguous global_load_lds). Fence-FREE fused finalize:
//   - epilogue atomicMins are device-scope RMWs at the coherent point
//   - s_waitcnt vmcnt(0) (local, no cache maintenance) before the relaxed
//     agent-scope done-counter bump
//   - last block reads min_enc via atomicMin(p, 0xFFFFFFFF) RMW-reads
//     (same coherent point -> immune to stale L2 lines), no __threadfence
//     anywhere (R4 lesson: threadfence/release => per-XCD L2 thrash).
// ---------------------------------------------------------------------------
__global__ __launch_bounds__(256) void gemm_min_kernel(
    const unsigned short* __restrict__ zb, const unsigned short* __restrict__ eb,
    const float* __restrict__ zsq, const float* __restrict__ esq,
    unsigned* __restrict__ min_enc, unsigned* __restrict__ ctrl,
    float* __restrict__ out) {
    __shared__ __align__(16) unsigned short As[2 * BM * BK];  // 16 KB
    __shared__ __align__(16) unsigned short Bs[2 * BN * BK];  // 16 KB
    __shared__ float zsq_s[BM];
    __shared__ float red[4];
    __shared__ int last_flag;

    const int t = threadIdx.x;
    const int bx = blockIdx.x;  // code (col) block
    const int by = blockIdx.y;  // point (row) block
    const int lane = t & 63;
    const int w = t >> 6;
    const int wm = w >> 1, wn = w & 1;
    const int lrow = lane & 15;
    const int q = lane >> 4;

    if (t < BM) zsq_s[t] = zsq[by * BM + t];

    f32x4 acc[4][4];
    #pragma unroll
    for (int i = 0; i < 4; i++)
        #pragma unroll
        for (int j = 0; j < 4; j++) acc[i][j] = (f32x4){0.f, 0.f, 0.f, 0.f};

    // staging geometry (per slice, R1-proven): thread t covers bytes
    // [t*16, t*16+16) of the 8 KB slice (instr 0) and +4096 B (instr 1).
    const int row0 = (t * 16) >> 6;         // 0..63
    const int kel0 = ((t * 16) & 63) >> 1;  // k-element offset 0/8/16/24
    const int lds_b0 = w * 512;             // wave-uniform LDS base (elements)
    const size_t a_base = (size_t)(by * BM) * ZDIM;
    const size_t b_base = (size_t)(bx * BN) * ZDIM;

    for (int k0 = 0; k0 < ZDIM; k0 += 2 * BK) {
        #pragma unroll
        for (int s = 0; s < 2; s++) {
            const unsigned short* ga0 =
                zb + a_base + (size_t)row0 * ZDIM + k0 + s * BK + kel0;
            const unsigned short* gb0 =
                eb + b_base + (size_t)row0 * ZDIM + k0 + s * BK + kel0;
            __builtin_amdgcn_global_load_lds(
                (const __attribute__((address_space(1))) void*)ga0,
                (__attribute__((address_space(3))) void*)(As + s * 4096 + lds_b0),
                16, 0, 0);
            __builtin_amdgcn_global_load_lds(
                (const __attribute__((address_space(1))) void*)(ga0 + (size_t)64 * ZDIM),
                (__attribute__((address_space(3))) void*)(As + s * 4096 + 2048 + lds_b0),
                16, 0, 0);
            __builtin_amdgcn_global_load_lds(
                (const __attribute__((address_space(1))) void*)gb0,
                (__attribute__((address_space(3))) void*)(Bs + s * 4096 + lds_b0),
                16, 0, 0);
            __builtin_amdgcn_global_load_lds(
                (const __attribute__((address_space(1))) void*)(gb0 + (size_t)64 * ZDIM),
                (__attribute__((address_space(3))) void*)(Bs + s * 4096 + 2048 + lds_b0),
                16, 0, 0);
        }
        __syncthreads();

        #pragma unroll
        for (int s = 0; s < 2; s++) {
            bf16x8 a[4], bb[4];
            #pragma unroll
            for (int am = 0; am < 4; am++)
                a[am] = *(const bf16x8*)(As + s * 4096 +
                                         (wm * 64 + am * 16 + lrow) * BK + q * 8);
            #pragma unroll
            for (int an = 0; an < 4; an++)
                bb[an] = *(const bf16x8*)(Bs + s * 4096 +
                                          (wn * 64 + an * 16 + lrow) * BK + q * 8);
            #pragma unroll
            for (int am = 0; am < 4; am++)
                #pragma unroll
                for (int an = 0; an < 4; an++)
                    acc[am][an] = __builtin_amdgcn_mfma_f32_16x16x32_bf16(
                        a[am], bb[an], acc[am][an], 0, 0, 0);
        }
        __syncthreads();
    }

    // Epilogue (R5-proven). C/D layout: row = q*4+r, col = lrow.
    #pragma unroll
    for (int an = 0; an < 4; an++) {
        float v = 3.4e38f;
        #pragma unroll
        for (int am = 0; am < 4; am++) {
            const int rbase = wm * 64 + am * 16 + q * 4;
            f32x4 c = acc[am][an];
            v = fminf(v, zsq_s[rbase + 0] - 2.f * c[0]);
            v = fminf(v, zsq_s[rbase + 1] - 2.f * c[1]);
            v = fminf(v, zsq_s[rbase + 2] - 2.f * c[2]);
            v = fminf(v, zsq_s[rbase + 3] - 2.f * c[3]);
        }
        v = fminf(v, __shfl_xor(v, 16, 64));
        v = fminf(v, __shfl_xor(v, 32, 64));
        if (q == 0) {
            const int col = bx * BN + wn * 64 + an * 16 + lrow;
            atomicMin(&min_enc[col], enc_f32(v));
        }
    }

    // Fence-free last-block finalize.
    __builtin_amdgcn_s_waitcnt(0x0F70);  // vmcnt(0) only: atomics complete
    __syncthreads();                     // whole block's atomics done
    if (t == 0) {
        unsigned old = __hip_atomic_fetch_add(&ctrl[0], 1u, __ATOMIC_RELAXED,
                                              __HIP_MEMORY_SCOPE_AGENT);
        last_flag = (old == (unsigned)(GRID_GEMM - 1));
    }
    __syncthreads();
    if (last_flag) {
        float s = 0.f;
        #pragma unroll
        for (int i = 0; i < M_CODES / 256; i++) {
            const int j = i * 256 + t;
            // RMW-read at the coherent point (value unchanged by min with max)
            unsigned enc = atomicMin(&min_enc[j], 0xFFFFFFFFu);
            s += dec_f32(enc) + esq[j];
        }
        #pragma unroll
        for (int off = 1; off < 64; off <<= 1) s += __shfl_xor(s, off, 64);
        if (lane == 0) red[w] = s;
        __syncthreads();
        if (t == 0)
            out[0] = (red[0] + red[1] + red[2] + red[3]) * (1.f / M_CODES);
    }
}

extern "C" void kernel_launch(void* const* d_in, const int* in_sizes, int n_in,
                              void* d_out, int out_size, void* d_ws, size_t ws_size,
                              hipStream_t stream) {
    (void)in_sizes; (void)n_in; (void)out_size; (void)ws_size;
    const float* z = (const float*)d_in[0];
    const float* e = (const float*)d_in[1];
    char* ws = (char*)d_ws;
    unsigned short* zb = (unsigned short*)ws;                            // 8 MB
    unsigned short* eb = (unsigned short*)(ws + ((size_t)8 << 20));      // 8 MB
    float* zsq = (float*)(ws + ((size_t)16 << 20));                      // 16 KB
    float* esq = (float*)(ws + ((size_t)16 << 20) + 16384);              // 16 KB
    unsigned* min_enc = (unsigned*)(ws + ((size_t)16 << 20) + 32768);    // 16 KB
    unsigned* ctrl = (unsigned*)(ws + ((size_t)16 << 20) + 49152);       // 16 B

    prep_kernel<<<dim3(1024), dim3(256), 0, stream>>>(
        z, e, zb, eb, zsq, esq, min_enc, ctrl);
    gemm_min_kernel<<<dim3(M_CODES / BN, N_PTS / BM), dim3(256), 0, stream>>>(
        zb, eb, zsq, esq, min_enc, ctrl, (float*)d_out);
}